// Round 1
// baseline (410.318 us; speedup 1.0000x reference)
//
#include <hip/hip_runtime.h>
#include <hip/hip_bf16.h>

#define NSIDE 128
#define NPIX (12 * NSIDE * NSIDE)   // 196608
#define BB 8
#define CIN 16
#define COUT 32
#define NROW (NPIX + 1)             // padded rows per batch

typedef _Float16 half8 __attribute__((ext_vector_type(8)));
typedef float floatx16 __attribute__((ext_vector_type(16)));

// Transpose + cast: x (B, CIN, NPIX) f32  ->  xt (B, NPIX+1, CIN) f16, pad row = 0
__global__ __launch_bounds__(256) void prep_xt(const float* __restrict__ x,
                                               _Float16* __restrict__ xt) {
    int r = blockIdx.x * 256 + threadIdx.x;
    const int total = BB * NROW;
    if (r >= total) return;
    int b = r / NROW;
    int p = r - b * NROW;
    half8 lo, hi;
    if (p < NPIX) {
        const float* xp = x + (long)b * CIN * NPIX + p;
#pragma unroll
        for (int c = 0; c < 8; c++) lo[c] = (_Float16)xp[(long)c * NPIX];
#pragma unroll
        for (int c = 0; c < 8; c++) hi[c] = (_Float16)xp[(long)(c + 8) * NPIX];
    } else {
#pragma unroll
        for (int c = 0; c < 8; c++) { lo[c] = (_Float16)0.f; hi[c] = (_Float16)0.f; }
    }
    *(half8*)(xt + (long)r * 16)     = lo;
    *(half8*)(xt + (long)r * 16 + 8) = hi;
}

// Weights (COUT, CIN, 9) f32 -> A-fragment layout wf[(k*64+lane)*8 + j] f16
// A[m=lane&31][kdim=(lane>>5)*8+j] where m=o, kdim=c, per neighbour-slot k.
__global__ __launch_bounds__(256) void prep_wf(const float* __restrict__ w,
                                               _Float16* __restrict__ wf) {
    for (int e = threadIdx.x; e < 9 * 64 * 8; e += 256) {
        int k    = e >> 9;         // e / 512
        int lane = (e >> 3) & 63;
        int j    = e & 7;
        int o    = lane & 31;
        int c    = ((lane >> 5) << 3) + j;
        wf[e] = (_Float16)w[(o * CIN + c) * 9 + k];
    }
}

// One wave per 32-pixel tile: out[32 o][32 p] = sum over 9 MFMAs (K=16=CIN each)
__global__ __launch_bounds__(256) void conv_main(const _Float16* __restrict__ xt,
                                                 const _Float16* __restrict__ wf,
                                                 const float* __restrict__ bias,
                                                 const int* __restrict__ nb,
                                                 float* __restrict__ out) {
    const int lane  = threadIdx.x & 63;
    const int wv    = threadIdx.x >> 6;
    const int tile  = blockIdx.x * 4 + wv;        // [0, BB*NPIX/32)
    const int b     = tile / (NPIX / 32);
    const int pt    = tile - b * (NPIX / 32);
    const int p     = pt * 32 + (lane & 31);
    const int chalf = (lane >> 5) * 8;

    half8 wfrag[9];
#pragma unroll
    for (int k = 0; k < 9; k++)
        wfrag[k] = *(const half8*)(wf + ((k * 64 + lane) << 3));

    const int* nbp = nb + p * 9;
    int idx[9];
#pragma unroll
    for (int k = 0; k < 9; k++) idx[k] = nbp[k];

    const _Float16* xb = xt + (long)b * NROW * 16 + chalf;
    floatx16 acc;
#pragma unroll
    for (int i = 0; i < 16; i++) acc[i] = 0.f;

#pragma unroll
    for (int k = 0; k < 9; k++) {
        half8 v = *(const half8*)(xb + (long)idx[k] * 16);
        acc = __builtin_amdgcn_mfma_f32_32x32x16_f16(wfrag[k], v, acc, 0, 0, 0);
    }

    // C/D layout: col(pixel)=lane&31, row(o)=(r&3)+8*(r>>2)+4*(lane>>5)
    float* outb = out + ((long)b * COUT) * NPIX + p;
#pragma unroll
    for (int r = 0; r < 16; r++) {
        int o = (r & 3) + ((r >> 2) << 3) + ((lane >> 5) << 2);
        outb[(long)o * NPIX] = acc[r] + bias[o];
    }
}

extern "C" void kernel_launch(void* const* d_in, const int* in_sizes, int n_in,
                              void* d_out, int out_size, void* d_ws, size_t ws_size,
                              hipStream_t stream) {
    const float* x    = (const float*)d_in[0];
    const float* w    = (const float*)d_in[1];
    const float* bias = (const float*)d_in[2];
    const int*   nb   = (const int*)d_in[3];
    float*       out  = (float*)d_out;

    _Float16* wf = (_Float16*)d_ws;                      // 9216 B
    _Float16* xt = (_Float16*)((char*)d_ws + 16384);     // 50.3 MB

    int rows = BB * NROW;
    hipLaunchKernelGGL(prep_xt, dim3((rows + 255) / 256), dim3(256), 0, stream, x, xt);
    hipLaunchKernelGGL(prep_wf, dim3(1), dim3(256), 0, stream, w, wf);
    hipLaunchKernelGGL(conv_main, dim3(BB * NPIX / 32 / 4), dim3(256), 0, stream,
                       xt, wf, bias, nb, out);
}